// Round 8
// baseline (361.060 us; speedup 1.0000x reference)
//
#include <hip/hip_runtime.h>
#include <math.h>

#define Cc 1000
#define Cpad 1024
#define Dd 256
#define Bb 16384
#define NSs 200000
#define MOM 0.1f
#define EPSV 1e-12f
#define EPSC 0.10f
#define CANDCAP 48
#define LISTCAP 40
#define NEG_BIG (-3.4e38f)
#define IDX_BIG 0x7fffffff

// d_out layout (floats), concat of reference return tuple
#define OUT_CENTER 0
#define OUT_SRC (Cc*Dd)                       // 256000
#define OUT_C2C (OUT_SRC + (size_t)NSs*Dd)    // 51,456,000
#define OUT_INTER (OUT_C2C + Cc*2)            // 51,458,000

// scratch inside out_src region (float offsets); consumed by k_fin before k_src overwrites
#define SCR_FB 0                               // ushort[Bb*Dd]      (2,097,152 floats)
#define SCR_CB 2097152                         // ushort[Cpad*Dd]    (131,072 floats)
#define SCR_PART 2228224                       // float4[Bb*16]      (1,048,576 floats)
#define SCR_CAND 3276800                       // float2[Bb*CANDCAP] (1,572,864 floats)
#define SCR_CNT 4849664                        // int[Bb]
// end ~4.85M floats << 51.2M region

// ws layout (floats) — total ~1.85 MB (proven)
#define WS_CHAT 0
#define WS_INVF 256000
#define WS_MARK 272384                         // int[NSs]

typedef __bf16 bf16x8 __attribute__((ext_vector_type(8)));
typedef float  f32x4  __attribute__((ext_vector_type(4)));

__device__ __forceinline__ ushort f2bf(float f) {
    uint u = __float_as_uint(f);
    u += 0x7FFFu + ((u >> 16) & 1u);   // round-to-nearest-even
    return (ushort)(u >> 16);
}

__device__ __forceinline__ void gload16(const void* g, void* l) {
    __builtin_amdgcn_global_load_lds(
        (const __attribute__((address_space(1))) void*)g,
        (__attribute__((address_space(3))) void*)l, 16, 0, 0);
}

__device__ __forceinline__ void upd_top2(float& s1, int& i1, float& s2, int& i2,
                                         float s, int i) {
    // jax.lax.top_k tie semantics: larger value first; equal values -> lower index first
    if (s > s1 || (s == s1 && i < i1)) {
        s2 = s1; i2 = i1; s1 = s; i1 = i;
    } else if (s > s2 || (s == s2 && i < i2)) {
        s2 = s; i2 = i;
    }
}

// ---------------- K_init: base copies (inter, c2c, center) + mark=-1 + cnt=0 ----------------
#define N_INTER4 (Cc*Cc*2/4)     // 500000
#define N_C2C4   (Cc*2/4)        // 500
#define N_CM4    (Cc*Dd/4)       // 64000
#define N_MARK4  (NSs/4)         // 50000
#define N_CNT4   (Bb/4)          // 4096
#define N_INIT4  (N_INTER4 + N_C2C4 + N_CM4 + N_MARK4 + N_CNT4)

__global__ void k_init(const float4* __restrict__ interdist,
                       const float4* __restrict__ c2c,
                       const float4* __restrict__ cmem,
                       float4* __restrict__ out_inter,
                       float4* __restrict__ out_c2c,
                       float4* __restrict__ out_center,
                       int4* __restrict__ mark, int4* __restrict__ cnt) {
    int i = blockIdx.x * blockDim.x + threadIdx.x;
    if (i < N_INTER4) {
        out_inter[i] = interdist[i];
    } else if (i < N_INTER4 + N_C2C4) {
        out_c2c[i - N_INTER4] = c2c[i - N_INTER4];
    } else if (i < N_INTER4 + N_C2C4 + N_CM4) {
        out_center[i - N_INTER4 - N_C2C4] = cmem[i - N_INTER4 - N_C2C4];
    } else if (i < N_INTER4 + N_C2C4 + N_CM4 + N_MARK4) {
        int4 m; m.x = -1; m.y = -1; m.z = -1; m.w = -1;
        mark[i - N_INTER4 - N_C2C4 - N_CM4] = m;
    } else if (i < N_INIT4) {
        int4 z; z.x = 0; z.y = 0; z.z = 0; z.w = 0;
        cnt[i - N_INTER4 - N_C2C4 - N_CM4 - N_MARK4] = z;
    }
}

// ---------------- K_scatter: mark[index[i]] = i ----------------
__global__ void k_scatter(const int* __restrict__ index, int* __restrict__ mark) {
    int i = blockIdx.x * blockDim.x + threadIdx.x;
    if (i < Bb) mark[index[i]] = i;
}

// ---------------- K1a: per-row norms, d1@label -> c2c, seg-sum atomics, feat->bf16 ----------------
__global__ void k_rows_a(const float* __restrict__ feat, const float* __restrict__ cmem,
                         const int* __restrict__ label,
                         float* __restrict__ out_center, float* __restrict__ out_c2c,
                         float* __restrict__ ws_invf, ushort* __restrict__ fb) {
    int wid  = threadIdx.x >> 6;
    int lane = threadIdx.x & 63;
    int row  = blockIdx.x * 4 + wid;
    if (row >= Bb) return;

    const float4 f4 = *(const float4*)(feat + (size_t)row * Dd + lane * 4);
    int lab = label[row];
    const float4 c4 = *(const float4*)(cmem + (size_t)lab * Dd + lane * 4);

    ushort4 h;
    h.x = f2bf(f4.x); h.y = f2bf(f4.y); h.z = f2bf(f4.z); h.w = f2bf(f4.w);
    *(ushort4*)(fb + (size_t)row * Dd + lane * 4) = h;

    float fs = f4.x*f4.x + f4.y*f4.y + f4.z*f4.z + f4.w*f4.w;
    float dt = f4.x*c4.x + f4.y*c4.y + f4.z*c4.z + f4.w*c4.w;
    float cs = c4.x*c4.x + c4.y*c4.y + c4.z*c4.z + c4.w*c4.w;
    #pragma unroll
    for (int off = 32; off; off >>= 1) {
        fs += __shfl_xor(fs, off);
        dt += __shfl_xor(dt, off);
        cs += __shfl_xor(cs, off);
    }
    float invf = 1.0f / fmaxf(sqrtf(fs), EPSV);
    if (lane == 0) {
        ws_invf[row] = invf;
        float invc = 1.0f / fmaxf(sqrtf(cs), EPSV);
        float d1 = 0.5f * (1.0f - dt * invf * invc);
        atomicAdd(out_c2c + lab * 2,     1.0f);
        atomicAdd(out_c2c + lab * 2 + 1, d1);
    }
    atomicAdd(out_center + (size_t)lab * Dd + lane * 4 + 0, f4.x);
    atomicAdd(out_center + (size_t)lab * Dd + lane * 4 + 1, f4.y);
    atomicAdd(out_center + (size_t)lab * Dd + lane * 4 + 2, f4.z);
    atomicAdd(out_center + (size_t)lab * Dd + lane * 4 + 3, f4.w);
}

// ---------------- K2: normalize center_new -> chat (f32) + chat_bf16 (padded to 1024) ----------------
__global__ void k_chat(const float* __restrict__ out_center, float* __restrict__ chat,
                       ushort* __restrict__ cb) {
    int c = blockIdx.x;      // 0..1023
    int lane = threadIdx.x;  // 64
    if (c >= Cc) {
        ushort4 z; z.x = 0; z.y = 0; z.z = 0; z.w = 0;
        *(ushort4*)(cb + (size_t)c * Dd + lane * 4) = z;
        return;
    }
    float4 v = *(const float4*)(out_center + (size_t)c * Dd + lane * 4);
    float ss = v.x*v.x + v.y*v.y + v.z*v.z + v.w*v.w;
    #pragma unroll
    for (int off = 32; off; off >>= 1) ss += __shfl_xor(ss, off);
    float inv = 1.0f / fmaxf(sqrtf(ss), EPSV);
    float4 r; r.x = v.x*inv; r.y = v.y*inv; r.z = v.z*inv; r.w = v.w*inv;
    *(float4*)(chat + (size_t)c * Dd + lane * 4) = r;
    ushort4 h;
    h.x = f2bf(r.x); h.y = f2bf(r.y); h.z = f2bf(r.z); h.w = f2bf(r.w);
    *(ushort4*)(cb + (size_t)c * Dd + lane * 4) = h;
}

// ---------------- K4: LDS-staged bf16 MFMA GEMM + fused per-tile top-2 ----------------
// R6's proven staging/MFMA (128x128 tile, BK=64, XOR-swizzle via pre-swizzled source)
// + R4's proven register-bounded reduction (one mi row-group at a time: only 16 extra
// regs beside the 64-reg acc; a/b frags dead by then). No scores buffer: saves 134MB.
__global__ __launch_bounds__(256, 2) void k_gemm(const ushort* __restrict__ fb,
                                                 const ushort* __restrict__ cb,
                                                 float4* __restrict__ part,
                                                 float2* __restrict__ cand,
                                                 int* __restrict__ cnt) {
    __shared__ __align__(16) char Asb[128 * 128];   // 16 KB
    __shared__ __align__(16) char Bsb[128 * 128];   // 16 KB

    int tid  = threadIdx.x;
    int wid  = tid >> 6;
    int lane = tid & 63;
    int rl = lane & 15;
    int kg = lane >> 4;
    int wr = wid >> 1;          // 0..1 row half
    int wc = wid & 1;           // 0..1 col half
    int row0 = blockIdx.y * 128;
    int c0   = blockIdx.x * 128;
    int tile = blockIdx.x * 2 + wc;   // 0..15 column chunk of 64

    // pre-swizzled source chunk: lane writes physical chunk (lane&7) of LDS row
    // rloc+(lane>>3); it must fetch logical chunk (lane&7)^(lane>>3)
    int realb = ((lane & 7) ^ (lane >> 3)) << 4;    // byte offset within 128B row

    f32x4 acc[4][4];
    f32x4 z = {0.f, 0.f, 0.f, 0.f};
    #pragma unroll
    for (int mi = 0; mi < 4; mi++)
        #pragma unroll
        for (int ni = 0; ni < 4; ni++)
            acc[mi][ni] = z;

    for (int t = 0; t < 4; t++) {           // K steps of 64
        // ---- stage: each wave loads 32 rows of A and of B (4 issues each, 8 rows/issue)
        #pragma unroll
        for (int i = 0; i < 4; i++) {
            int rloc = wid * 32 + i * 8;
            int grow = row0 + rloc + (lane >> 3);
            gload16((const char*)(fb + (size_t)grow * Dd) + t * 128 + realb,
                    Asb + rloc * 128);
        }
        #pragma unroll
        for (int i = 0; i < 4; i++) {
            int rloc = wid * 32 + i * 8;
            int gcol = c0 + rloc + (lane >> 3);
            gload16((const char*)(cb + (size_t)gcol * Dd) + t * 128 + realb,
                    Bsb + rloc * 128);
        }
        asm volatile("s_waitcnt vmcnt(0)" ::: "memory");
        __syncthreads();

        // ---- fragments: swizzled ds_read_b128
        bf16x8 a[4][2], b[4][2];
        #pragma unroll
        for (int mi = 0; mi < 4; mi++)
            #pragma unroll
            for (int ks = 0; ks < 2; ks++) {
                int r = wr * 64 + mi * 16 + rl;
                int off = r * 128 + ((ks * 64 + kg * 16) ^ ((r & 7) << 4));
                a[mi][ks] = *(const bf16x8*)(Asb + off);
            }
        #pragma unroll
        for (int ni = 0; ni < 4; ni++)
            #pragma unroll
            for (int ks = 0; ks < 2; ks++) {
                int r = wc * 64 + ni * 16 + rl;
                int off = r * 128 + ((ks * 64 + kg * 16) ^ ((r & 7) << 4));
                b[ni][ks] = *(const bf16x8*)(Bsb + off);
            }

        // ---- 32 MFMAs
        #pragma unroll
        for (int ks = 0; ks < 2; ks++)
            #pragma unroll
            for (int mi = 0; mi < 4; mi++)
                #pragma unroll
                for (int ni = 0; ni < 4; ni++)
                    acc[mi][ni] = __builtin_amdgcn_mfma_f32_16x16x32_bf16(
                        a[mi][ks], b[ni][ks], acc[mi][ni], 0, 0, 0);

        __syncthreads();   // before next stage overwrites LDS
    }

    // ---- fused reduction: one mi row-group (16 rows) at a time ----
    // acc[mi][ni][rr] -> row = row0 + wr*64 + mi*16 + kg*4 + rr, col = c0 + wc*64 + ni*16 + rl
    #pragma unroll
    for (int mi = 0; mi < 4; mi++) {
        float S1[4], S2[4];
        int   I1[4], I2[4];
        #pragma unroll
        for (int r = 0; r < 4; r++) { S1[r] = NEG_BIG; S2[r] = NEG_BIG; I1[r] = IDX_BIG; I2[r] = IDX_BIG; }
        #pragma unroll
        for (int ni = 0; ni < 4; ni++) {
            int col = c0 + wc * 64 + ni * 16 + rl;
            if (col < Cc) {
                #pragma unroll
                for (int r = 0; r < 4; r++)
                    upd_top2(S1[r], I1[r], S2[r], I2[r], acc[mi][ni][r], col);
            }
        }
        // butterfly across the 16-lane rl group (disjoint col sets -> no dupes)
        #pragma unroll
        for (int off = 1; off < 16; off <<= 1) {
            #pragma unroll
            for (int r = 0; r < 4; r++) {
                float t1 = __shfl_xor(S1[r], off), t2 = __shfl_xor(S2[r], off);
                int   u1 = __shfl_xor(I1[r], off), u2 = __shfl_xor(I2[r], off);
                upd_top2(S1[r], I1[r], S2[r], I2[r], t1, u1);
                upd_top2(S1[r], I1[r], S2[r], I2[r], t2, u2);
            }
        }
        // emit rare extras: within EPSC of tile-2nd-max, not the tile top2
        #pragma unroll
        for (int ni = 0; ni < 4; ni++) {
            int col = c0 + wc * 64 + ni * 16 + rl;
            #pragma unroll
            for (int r = 0; r < 4; r++) {
                float v = acc[mi][ni][r];
                if (col < Cc && v >= S2[r] - EPSC && col != I1[r] && col != I2[r]) {
                    int row = row0 + wr * 64 + mi * 16 + kg * 4 + r;
                    int slot = atomicAdd(cnt + row, 1);
                    if (slot < CANDCAP)
                        cand[(size_t)row * CANDCAP + slot] = make_float2(v, __int_as_float(col));
                }
            }
        }
        // per-tile top2 partials: lane rl==r writes row-slot r (static index)
        #pragma unroll
        for (int r = 0; r < 4; r++) {
            if (rl == r) {
                int row = row0 + wr * 64 + mi * 16 + kg * 4 + r;
                part[(size_t)row * 16 + tile] =
                    make_float4(S1[r], S2[r], __int_as_float(I1[r]), __int_as_float(I2[r]));
            }
        }
    }
}

// ---------------- K5: merge 16 tile partials, filter by global s2-EPSC, f32 rescore ----------------
__global__ __launch_bounds__(256) void k_fin(const float4* __restrict__ part,
                                             const float2* __restrict__ cand,
                                             const int* __restrict__ cnt,
                                             const float* __restrict__ feat,
                                             const float* __restrict__ chat,
                                             const float* __restrict__ ws_invf,
                                             float* __restrict__ out_inter) {
    __shared__ int lcnt[4];
    __shared__ int lst[4][LISTCAP];
    int wid  = threadIdx.x >> 6;
    int lane = threadIdx.x & 63;
    int row  = blockIdx.x * 4 + wid;
    if (lane == 0) lcnt[wid] = 0;

    float4 p;
    if (lane < 16) p = part[(size_t)row * 16 + lane];
    else p = make_float4(NEG_BIG, NEG_BIG, __int_as_float(IDX_BIG), __int_as_float(IDX_BIG));

    float s1 = p.x, s2 = p.y;
    int   i1 = __float_as_int(p.z), i2 = __float_as_int(p.w);
    #pragma unroll
    for (int off = 1; off < 64; off <<= 1) {
        float t1 = __shfl_xor(s1, off), t2 = __shfl_xor(s2, off);
        int   u1 = __shfl_xor(i1, off), u2 = __shfl_xor(i2, off);
        upd_top2(s1, i1, s2, i2, t1, u1);
        upd_top2(s1, i1, s2, i2, t2, u2);
    }
    float thr = s2 - EPSC;
    if (lane < 16) {
        if (p.x >= thr) { int s = atomicAdd(&lcnt[wid], 1); if (s < LISTCAP) lst[wid][s] = __float_as_int(p.z); }
        if (p.y >= thr) { int s = atomicAdd(&lcnt[wid], 1); if (s < LISTCAP) lst[wid][s] = __float_as_int(p.w); }
    }
    int n = cnt[row]; if (n > CANDCAP) n = CANDCAP;
    if (lane < n) {
        float2 cv = cand[(size_t)row * CANDCAP + lane];
        if (cv.x >= thr) { int s = atomicAdd(&lcnt[wid], 1); if (s < LISTCAP) lst[wid][s] = __float_as_int(cv.y); }
    }
    __syncthreads();
    int m = lcnt[wid]; if (m > LISTCAP) m = LISTCAP;

    const float4 f4 = *(const float4*)(feat + (size_t)row * Dd + lane * 4);
    float F1 = NEG_BIG, F2 = NEG_BIG;
    int   J1 = IDX_BIG, J2 = IDX_BIG;
    for (int k = 0; k < m; k++) {
        int col = lst[wid][k];
        const float4 c4 = *(const float4*)(chat + (size_t)col * Dd + lane * 4);
        float d = f4.x*c4.x + f4.y*c4.y + f4.z*c4.z + f4.w*c4.w;
        #pragma unroll
        for (int off = 32; off; off >>= 1) d += __shfl_xor(d, off);
        upd_top2(F1, J1, F2, J2, d, col);   // order-independent
    }
    if (lane == 0) {
        float inter = 0.5f * ws_invf[row] * (F1 - F2);
        size_t off2 = ((size_t)J1 * Cc + J2) * 2;
        atomicAdd(out_inter + off2,     1.0f);
        atomicAdd(out_inter + off2 + 1, inter);
    }
}

// ---------------- K3: single-pass source_mem copy/lerp (NT on the 410MB stream) ----------------
__global__ void k_src(const float* __restrict__ src, const float* __restrict__ feat,
                      const int* __restrict__ mark, float* __restrict__ dst) {
    const int n4 = NSs * Dd / 4;   // 12,800,000
    int stride = gridDim.x * blockDim.x;
    for (int e = blockIdx.x * blockDim.x + threadIdx.x; e < n4; e += stride) {
        int row = e >> 6;            // Dd/4 = 64 float4 per row
        int m = mark[row];
        f32x4 v = __builtin_nontemporal_load((const f32x4*)src + e);
        if (m >= 0) {
            f32x4 f = *((const f32x4*)feat + (size_t)m * 64 + (e & 63));
            v = (1.0f - MOM) * v + MOM * f;
        }
        __builtin_nontemporal_store(v, (f32x4*)dst + e);
    }
}

extern "C" void kernel_launch(void* const* d_in, const int* in_sizes, int n_in,
                              void* d_out, int out_size, void* d_ws, size_t ws_size,
                              hipStream_t stream) {
    const float* feat   = (const float*)d_in[0];
    const float* cmem   = (const float*)d_in[1];
    const float* smem   = (const float*)d_in[2];
    const float* c2c    = (const float*)d_in[3];
    const float* inter  = (const float*)d_in[4];
    const int*   label  = (const int*)d_in[5];
    const int*   index  = (const int*)d_in[6];

    float* out = (float*)d_out;
    float* out_center = out + OUT_CENTER;
    float* out_src    = out + OUT_SRC;
    float* out_c2c    = out + OUT_C2C;
    float* out_inter  = out + OUT_INTER;

    float* ws    = (float*)d_ws;
    float* chat  = ws + WS_CHAT;
    float* winvf = ws + WS_INVF;
    int*   mark  = (int*)(ws + WS_MARK);

    // scratch inside out_src region (consumed by k_fin before k_src overwrites)
    ushort* fb    = (ushort*)(out_src + SCR_FB);
    ushort* cb    = (ushort*)(out_src + SCR_CB);
    float4* part  = (float4*)(out_src + SCR_PART);
    float2* cand  = (float2*)(out_src + SCR_CAND);
    int*    cnt   = (int*)(out_src + SCR_CNT);

    // 1) base copies + mark/cnt init
    k_init<<<(N_INIT4 + 255) / 256, 256, 0, stream>>>(
        (const float4*)inter, (const float4*)c2c, (const float4*)cmem,
        (float4*)out_inter, (float4*)out_c2c, (float4*)out_center,
        (int4*)mark, (int4*)cnt);
    // 2) scatter index -> mark
    k_scatter<<<Bb / 256, 256, 0, stream>>>(index, mark);
    // 3) per-row norms, c2c, center atomics, feat->bf16
    k_rows_a<<<Bb / 4, 256, 0, stream>>>(feat, cmem, label, out_center, out_c2c, winvf, fb);
    // 4) normalize center_new -> chat + chat_bf16 (padded)
    k_chat<<<Cpad, 64, 0, stream>>>(out_center, chat, cb);
    // 5) LDS-staged MFMA GEMM + fused top2 partials/extras
    {
        dim3 grid(Cpad / 128, Bb / 128);   // (8, 128)
        k_gemm<<<grid, 256, 0, stream>>>(fb, cb, part, cand, cnt);
    }
    // 6) merge + f32 rescore -> interdist atomics (before scratch is overwritten)
    k_fin<<<Bb / 4, 256, 0, stream>>>(part, cand, cnt, feat, chat, winvf, out_inter);
    // 7) single-pass source_mem copy/lerp (overwrites scratch region)
    k_src<<<4096, 256, 0, stream>>>(smem, feat, mark, out_src);
}

// Round 9
// 262.129 us; speedup vs baseline: 1.3774x; 1.3774x over previous
//
#include <hip/hip_runtime.h>
#include <math.h>

#define Cc 1000
#define Cpad 1024
#define Dd 256
#define Bb 16384
#define NSs 200000
#define MOM 0.1f
#define EPSV 1e-12f
#define EPSC 0.10f
#define NEG_BIG (-3.4e38f)
#define IDX_BIG 0x7fffffff

// d_out layout (floats), concat of reference return tuple
#define OUT_CENTER 0
#define OUT_SRC (Cc*Dd)                       // 256000
#define OUT_C2C (OUT_SRC + (size_t)NSs*Dd)    // 51,456,000
#define OUT_INTER (OUT_C2C + Cc*2)            // 51,458,000

// scratch inside out_src region (float offsets); consumed by k_sel before k_src overwrites
#define SCR_SCORES 0                           // _Float16[Bb*Cpad] = 8,388,608 floats
#define SCR_FB 8388608                         // ushort[Bb*Dd]   (2,097,152 floats)
#define SCR_CB (SCR_FB + 2097152)              // ushort[Cpad*Dd] (131,072 floats)
// end ~10.6M floats << 51.2M region

// ws layout (floats) — total ~1.85 MB (proven)
#define WS_CHAT 0
#define WS_INVF 256000
#define WS_MARK 272384                         // int[NSs]

typedef __bf16    bf16x8 __attribute__((ext_vector_type(8)));
typedef float     f32x4  __attribute__((ext_vector_type(4)));
typedef _Float16  f16x8  __attribute__((ext_vector_type(8)));

__device__ __forceinline__ ushort f2bf(float f) {
    uint u = __float_as_uint(f);
    u += 0x7FFFu + ((u >> 16) & 1u);   // round-to-nearest-even
    return (ushort)(u >> 16);
}

__device__ __forceinline__ void gload16(const void* g, void* l) {
    __builtin_amdgcn_global_load_lds(
        (const __attribute__((address_space(1))) void*)g,
        (__attribute__((address_space(3))) void*)l, 16, 0, 0);
}

__device__ __forceinline__ void upd_top2(float& s1, int& i1, float& s2, int& i2,
                                         float s, int i) {
    // jax.lax.top_k tie semantics: larger value first; equal values -> lower index first
    if (s > s1 || (s == s1 && i < i1)) {
        s2 = s1; i2 = i1; s1 = s; i1 = i;
    } else if (s > s2 || (s == s2 && i < i2)) {
        s2 = s; i2 = i;
    }
}

// ---------------- K_init: base copies (inter, c2c, center) + mark=-1 ----------------
#define N_INTER4 (Cc*Cc*2/4)     // 500000
#define N_C2C4   (Cc*2/4)        // 500
#define N_CM4    (Cc*Dd/4)       // 64000
#define N_MARK4  (NSs/4)         // 50000
#define N_INIT4  (N_INTER4 + N_C2C4 + N_CM4 + N_MARK4)

__global__ void k_init(const float4* __restrict__ interdist,
                       const float4* __restrict__ c2c,
                       const float4* __restrict__ cmem,
                       float4* __restrict__ out_inter,
                       float4* __restrict__ out_c2c,
                       float4* __restrict__ out_center,
                       int4* __restrict__ mark) {
    int i = blockIdx.x * blockDim.x + threadIdx.x;
    if (i < N_INTER4) {
        out_inter[i] = interdist[i];
    } else if (i < N_INTER4 + N_C2C4) {
        out_c2c[i - N_INTER4] = c2c[i - N_INTER4];
    } else if (i < N_INTER4 + N_C2C4 + N_CM4) {
        out_center[i - N_INTER4 - N_C2C4] = cmem[i - N_INTER4 - N_C2C4];
    } else if (i < N_INIT4) {
        int4 m; m.x = -1; m.y = -1; m.z = -1; m.w = -1;
        mark[i - N_INTER4 - N_C2C4 - N_CM4] = m;
    }
}

// ---------------- K_scatter: mark[index[i]] = i ----------------
__global__ void k_scatter(const int* __restrict__ index, int* __restrict__ mark) {
    int i = blockIdx.x * blockDim.x + threadIdx.x;
    if (i < Bb) mark[index[i]] = i;
}

// ---------------- K1a: per-row norms, d1@label -> c2c, seg-sum atomics, feat->bf16 ----------------
__global__ void k_rows_a(const float* __restrict__ feat, const float* __restrict__ cmem,
                         const int* __restrict__ label,
                         float* __restrict__ out_center, float* __restrict__ out_c2c,
                         float* __restrict__ ws_invf, ushort* __restrict__ fb) {
    int wid  = threadIdx.x >> 6;
    int lane = threadIdx.x & 63;
    int row  = blockIdx.x * 4 + wid;
    if (row >= Bb) return;

    const float4 f4 = *(const float4*)(feat + (size_t)row * Dd + lane * 4);
    int lab = label[row];
    const float4 c4 = *(const float4*)(cmem + (size_t)lab * Dd + lane * 4);

    ushort4 h;
    h.x = f2bf(f4.x); h.y = f2bf(f4.y); h.z = f2bf(f4.z); h.w = f2bf(f4.w);
    *(ushort4*)(fb + (size_t)row * Dd + lane * 4) = h;

    float fs = f4.x*f4.x + f4.y*f4.y + f4.z*f4.z + f4.w*f4.w;
    float dt = f4.x*c4.x + f4.y*c4.y + f4.z*c4.z + f4.w*c4.w;
    float cs = c4.x*c4.x + c4.y*c4.y + c4.z*c4.z + c4.w*c4.w;
    #pragma unroll
    for (int off = 32; off; off >>= 1) {
        fs += __shfl_xor(fs, off);
        dt += __shfl_xor(dt, off);
        cs += __shfl_xor(cs, off);
    }
    float invf = 1.0f / fmaxf(sqrtf(fs), EPSV);
    if (lane == 0) {
        ws_invf[row] = invf;
        float invc = 1.0f / fmaxf(sqrtf(cs), EPSV);
        float d1 = 0.5f * (1.0f - dt * invf * invc);
        atomicAdd(out_c2c + lab * 2,     1.0f);
        atomicAdd(out_c2c + lab * 2 + 1, d1);
    }
    atomicAdd(out_center + (size_t)lab * Dd + lane * 4 + 0, f4.x);
    atomicAdd(out_center + (size_t)lab * Dd + lane * 4 + 1, f4.y);
    atomicAdd(out_center + (size_t)lab * Dd + lane * 4 + 2, f4.z);
    atomicAdd(out_center + (size_t)lab * Dd + lane * 4 + 3, f4.w);
}

// ---------------- K2: normalize center_new -> chat (f32) + chat_bf16 (padded to 1024) ----------------
__global__ void k_chat(const float* __restrict__ out_center, float* __restrict__ chat,
                       ushort* __restrict__ cb) {
    int c = blockIdx.x;      // 0..1023
    int lane = threadIdx.x;  // 64
    if (c >= Cc) {
        ushort4 z; z.x = 0; z.y = 0; z.z = 0; z.w = 0;
        *(ushort4*)(cb + (size_t)c * Dd + lane * 4) = z;
        return;
    }
    float4 v = *(const float4*)(out_center + (size_t)c * Dd + lane * 4);
    float ss = v.x*v.x + v.y*v.y + v.z*v.z + v.w*v.w;
    #pragma unroll
    for (int off = 32; off; off >>= 1) ss += __shfl_xor(ss, off);
    float inv = 1.0f / fmaxf(sqrtf(ss), EPSV);
    float4 r; r.x = v.x*inv; r.y = v.y*inv; r.z = v.z*inv; r.w = v.w*inv;
    *(float4*)(chat + (size_t)c * Dd + lane * 4) = r;
    ushort4 h;
    h.x = f2bf(r.x); h.y = f2bf(r.y); h.z = f2bf(r.z); h.w = f2bf(r.w);
    *(ushort4*)(cb + (size_t)c * Dd + lane * 4) = h;
}

// ---------------- K4: LDS-staged bf16 MFMA GEMM (R6-proven), scores fp16 out ----------------
// Block tile 128x128, BK=64, 4 waves each owning a 64x64 quadrant. XOR-swizzled LDS
// via pre-swizzled global source (rule 21). Epilogue stores fp16 (33MB, half of R6).
// NOTE: fusion of top-2 into this kernel spilled twice (R3: 386MB, R8: 189MB scratch
// writes) — the reduction state next to the live 64-reg acc defeats the allocator.
__global__ __launch_bounds__(256, 2) void k_gemm(const ushort* __restrict__ fb,
                                                 const ushort* __restrict__ cb,
                                                 _Float16* __restrict__ scores) {
    __shared__ __align__(16) char Asb[128 * 128];   // 16 KB
    __shared__ __align__(16) char Bsb[128 * 128];   // 16 KB

    int tid  = threadIdx.x;
    int wid  = tid >> 6;
    int lane = tid & 63;
    int rl = lane & 15;
    int kg = lane >> 4;
    int wr = wid >> 1;          // 0..1 row half
    int wc = wid & 1;           // 0..1 col half
    int row0 = blockIdx.y * 128;
    int c0   = blockIdx.x * 128;

    // pre-swizzled source chunk: lane writes physical chunk (lane&7) of LDS row
    // rloc+(lane>>3); it must fetch logical chunk (lane&7)^(lane>>3)
    int realb = ((lane & 7) ^ (lane >> 3)) << 4;    // byte offset within 128B row

    f32x4 acc[4][4];
    f32x4 z = {0.f, 0.f, 0.f, 0.f};
    #pragma unroll
    for (int mi = 0; mi < 4; mi++)
        #pragma unroll
        for (int ni = 0; ni < 4; ni++)
            acc[mi][ni] = z;

    for (int t = 0; t < 4; t++) {           // K steps of 64
        // ---- stage: each wave loads 32 rows of A and of B (4 issues each, 8 rows/issue)
        #pragma unroll
        for (int i = 0; i < 4; i++) {
            int rloc = wid * 32 + i * 8;
            int grow = row0 + rloc + (lane >> 3);
            gload16((const char*)(fb + (size_t)grow * Dd) + t * 128 + realb,
                    Asb + rloc * 128);
        }
        #pragma unroll
        for (int i = 0; i < 4; i++) {
            int rloc = wid * 32 + i * 8;
            int gcol = c0 + rloc + (lane >> 3);
            gload16((const char*)(cb + (size_t)gcol * Dd) + t * 128 + realb,
                    Bsb + rloc * 128);
        }
        asm volatile("s_waitcnt vmcnt(0)" ::: "memory");
        __syncthreads();

        // ---- fragments: swizzled ds_read_b128
        bf16x8 a[4][2], b[4][2];
        #pragma unroll
        for (int mi = 0; mi < 4; mi++)
            #pragma unroll
            for (int ks = 0; ks < 2; ks++) {
                int r = wr * 64 + mi * 16 + rl;
                int off = r * 128 + ((ks * 64 + kg * 16) ^ ((r & 7) << 4));
                a[mi][ks] = *(const bf16x8*)(Asb + off);
            }
        #pragma unroll
        for (int ni = 0; ni < 4; ni++)
            #pragma unroll
            for (int ks = 0; ks < 2; ks++) {
                int r = wc * 64 + ni * 16 + rl;
                int off = r * 128 + ((ks * 64 + kg * 16) ^ ((r & 7) << 4));
                b[ni][ks] = *(const bf16x8*)(Bsb + off);
            }

        // ---- 32 MFMAs
        #pragma unroll
        for (int ks = 0; ks < 2; ks++)
            #pragma unroll
            for (int mi = 0; mi < 4; mi++)
                #pragma unroll
                for (int ni = 0; ni < 4; ni++)
                    acc[mi][ni] = __builtin_amdgcn_mfma_f32_16x16x32_bf16(
                        a[mi][ks], b[ni][ks], acc[mi][ni], 0, 0, 0);

        __syncthreads();   // before next stage overwrites LDS
    }

    // ---- epilogue: C/D layout col=lane&15, row=(lane>>4)*4+reg [m89]; fp16 stores
    #pragma unroll
    for (int mi = 0; mi < 4; mi++) {
        int row = row0 + wr * 64 + mi * 16 + kg * 4;
        #pragma unroll
        for (int ni = 0; ni < 4; ni++) {
            int col = c0 + wc * 64 + ni * 16 + rl;
            #pragma unroll
            for (int rr = 0; rr < 4; rr++)
                scores[(size_t)(row + rr) * Cpad + col] = (_Float16)acc[mi][ni][rr];
        }
    }
}

// ---------------- K5: per-row exact top-2 of fp16 scores + f32 rescore of near-top candidates ----------------
__global__ __launch_bounds__(256) void k_sel(const _Float16* __restrict__ scores,
                                             const float* __restrict__ feat,
                                             const float* __restrict__ chat,
                                             const float* __restrict__ ws_invf,
                                             float* __restrict__ out_inter) {
    __shared__ int cnt[4];
    __shared__ int clist[4][32];
    int wid  = threadIdx.x >> 6;
    int lane = threadIdx.x & 63;
    int row  = blockIdx.x * 4 + wid;
    if (lane == 0) cnt[wid] = 0;

    const f16x8* sp = (const f16x8*)(scores + (size_t)row * Cpad);
    float v[16];
    float s1 = NEG_BIG, s2 = NEG_BIG;
    int   i1 = IDX_BIG, i2 = IDX_BIG;
    #pragma unroll
    for (int k = 0; k < 2; k++) {
        f16x8 q = sp[k * 64 + lane];            // cols k*512 + lane*8 .. +7 (coalesced 16B)
        int cbase = k * 512 + lane * 8;
        #pragma unroll
        for (int e = 0; e < 8; e++) {
            float f = (float)q[e];
            v[k*8 + e] = f;
            int c = cbase + e;
            if (c < Cc) upd_top2(s1, i1, s2, i2, f, c);
        }
    }
    // butterfly merge (disjoint column sets per lane -> no duplicate insertions)
    #pragma unroll
    for (int off = 1; off < 64; off <<= 1) {
        float ps1 = __shfl_xor(s1, off), ps2 = __shfl_xor(s2, off);
        int   pi1 = __shfl_xor(i1, off), pi2 = __shfl_xor(i2, off);
        upd_top2(s1, i1, s2, i2, ps1, pi1);
        upd_top2(s1, i1, s2, i2, ps2, pi2);
    }
    // candidates: every col with approx score within EPSC of the 2nd max
    float thr = s2 - EPSC;
    #pragma unroll
    for (int j = 0; j < 16; j++) {
        int c = (j >> 3) * 512 + lane * 8 + (j & 7);
        if (v[j] >= thr && c < Cc) {
            int slot = atomicAdd(&cnt[wid], 1);
            if (slot < 32) clist[wid][slot] = c;
        }
    }
    __syncthreads();
    int n = cnt[wid]; if (n > 32) n = 32;

    const float4 f4 = *(const float4*)(feat + (size_t)row * Dd + lane * 4);
    float S1 = NEG_BIG, S2 = NEG_BIG;
    int   I1 = IDX_BIG, I2 = IDX_BIG;
    for (int k = 0; k < n; k++) {
        int c = clist[wid][k];
        const float4 c4 = *(const float4*)(chat + (size_t)c * Dd + lane * 4);
        float d = f4.x*c4.x + f4.y*c4.y + f4.z*c4.z + f4.w*c4.w;
        #pragma unroll
        for (int off = 32; off; off >>= 1) d += __shfl_xor(d, off);
        upd_top2(S1, I1, S2, I2, d, c);   // order-independent result
    }
    if (lane == 0) {
        float inter = 0.5f * ws_invf[row] * (S1 - S2);
        size_t off2 = ((size_t)I1 * Cc + I2) * 2;
        atomicAdd(out_inter + off2,     1.0f);
        atomicAdd(out_inter + off2 + 1, inter);
    }
}

// ---------------- K3: single-pass source_mem copy/lerp (NT on the 410MB stream) ----------------
__global__ void k_src(const float* __restrict__ src, const float* __restrict__ feat,
                      const int* __restrict__ mark, float* __restrict__ dst) {
    const int n4 = NSs * Dd / 4;   // 12,800,000
    int stride = gridDim.x * blockDim.x;
    for (int e = blockIdx.x * blockDim.x + threadIdx.x; e < n4; e += stride) {
        int row = e >> 6;            // Dd/4 = 64 float4 per row
        int m = mark[row];
        f32x4 v = __builtin_nontemporal_load((const f32x4*)src + e);
        if (m >= 0) {
            f32x4 f = *((const f32x4*)feat + (size_t)m * 64 + (e & 63));
            v = (1.0f - MOM) * v + MOM * f;
        }
        __builtin_nontemporal_store(v, (f32x4*)dst + e);
    }
}

extern "C" void kernel_launch(void* const* d_in, const int* in_sizes, int n_in,
                              void* d_out, int out_size, void* d_ws, size_t ws_size,
                              hipStream_t stream) {
    const float* feat   = (const float*)d_in[0];
    const float* cmem   = (const float*)d_in[1];
    const float* smem   = (const float*)d_in[2];
    const float* c2c    = (const float*)d_in[3];
    const float* inter  = (const float*)d_in[4];
    const int*   label  = (const int*)d_in[5];
    const int*   index  = (const int*)d_in[6];

    float* out = (float*)d_out;
    float* out_center = out + OUT_CENTER;
    float* out_src    = out + OUT_SRC;
    float* out_c2c    = out + OUT_C2C;
    float* out_inter  = out + OUT_INTER;

    float* ws    = (float*)d_ws;
    float* chat  = ws + WS_CHAT;
    float* winvf = ws + WS_INVF;
    int*   mark  = (int*)(ws + WS_MARK);

    // scratch inside out_src region (consumed by k_sel before k_src overwrites)
    _Float16* scores = (_Float16*)(out_src + SCR_SCORES);
    ushort*   fb     = (ushort*)(out_src + SCR_FB);
    ushort*   cb     = (ushort*)(out_src + SCR_CB);

    // 1) base copies + mark init
    k_init<<<(N_INIT4 + 255) / 256, 256, 0, stream>>>(
        (const float4*)inter, (const float4*)c2c, (const float4*)cmem,
        (float4*)out_inter, (float4*)out_c2c, (float4*)out_center,
        (int4*)mark);
    // 2) scatter index -> mark
    k_scatter<<<Bb / 256, 256, 0, stream>>>(index, mark);
    // 3) per-row norms, c2c, center atomics, feat->bf16
    k_rows_a<<<Bb / 4, 256, 0, stream>>>(feat, cmem, label, out_center, out_c2c, winvf, fb);
    // 4) normalize center_new -> chat + chat_bf16 (padded)
    k_chat<<<Cpad, 64, 0, stream>>>(out_center, chat, cb);
    // 5) LDS-staged MFMA GEMM -> fp16 scores
    {
        dim3 grid(Cpad / 128, Bb / 128);   // (8, 128)
        k_gemm<<<grid, 256, 0, stream>>>(fb, cb, scores);
    }
    // 6) top-2 + f32 rescore -> interdist atomics (before scratch is overwritten)
    k_sel<<<Bb / 4, 256, 0, stream>>>(scores, feat, chat, winvf, out_inter);
    // 7) single-pass source_mem copy/lerp (overwrites scratch region)
    k_src<<<4096, 256, 0, stream>>>(smem, feat, mark, out_src);
}

// Round 10
// 261.360 us; speedup vs baseline: 1.3815x; 1.0029x over previous
//
#include <hip/hip_runtime.h>
#include <math.h>

#define Cc 1000
#define Cpad 1024
#define Dd 256
#define Bb 16384
#define NSs 200000
#define MOM 0.1f
#define EPSV 1e-12f
#define EPSC 0.10f
#define NEG_BIG (-3.4e38f)
#define IDX_BIG 0x7fffffff

// d_out layout (floats), concat of reference return tuple
#define OUT_CENTER 0
#define OUT_SRC (Cc*Dd)                       // 256000
#define OUT_C2C (OUT_SRC + (size_t)NSs*Dd)    // 51,456,000
#define OUT_INTER (OUT_C2C + Cc*2)            // 51,458,000

// scratch inside out_src region (float offsets); consumed by k_sel before k_src overwrites
#define SCR_SCORES 0                           // _Float16[Bb*Cpad] = 8,388,608 floats
#define SCR_FB 8388608                         // ushort[Bb*Dd]   (2,097,152 floats)
#define SCR_CB (SCR_FB + 2097152)              // ushort[Cpad*Dd] (131,072 floats)
// end ~10.6M floats << 51.2M region

// ws layout (floats) — total ~1.85 MB (proven)
#define WS_CHAT 0
#define WS_INVF 256000
#define WS_MARK 272384                         // int[NSs]

typedef __bf16    bf16x8 __attribute__((ext_vector_type(8)));
typedef float     f32x4  __attribute__((ext_vector_type(4)));
typedef _Float16  f16x8  __attribute__((ext_vector_type(8)));

__device__ __forceinline__ ushort f2bf(float f) {
    uint u = __float_as_uint(f);
    u += 0x7FFFu + ((u >> 16) & 1u);   // round-to-nearest-even
    return (ushort)(u >> 16);
}

__device__ __forceinline__ void gload16(const void* g, void* l) {
    __builtin_amdgcn_global_load_lds(
        (const __attribute__((address_space(1))) void*)g,
        (__attribute__((address_space(3))) void*)l, 16, 0, 0);
}

__device__ __forceinline__ void upd_top2(float& s1, int& i1, float& s2, int& i2,
                                         float s, int i) {
    // jax.lax.top_k tie semantics: larger value first; equal values -> lower index first
    if (s > s1 || (s == s1 && i < i1)) {
        s2 = s1; i2 = i1; s1 = s; i1 = i;
    } else if (s > s2 || (s == s2 && i < i2)) {
        s2 = s; i2 = i;
    }
}

// ---------------- K_init: base copies (inter, c2c, center) + mark=-1 ----------------
#define N_INTER4 (Cc*Cc*2/4)     // 500000
#define N_C2C4   (Cc*2/4)        // 500
#define N_CM4    (Cc*Dd/4)       // 64000
#define N_MARK4  (NSs/4)         // 50000
#define N_INIT4  (N_INTER4 + N_C2C4 + N_CM4 + N_MARK4)

__global__ void k_init(const float4* __restrict__ interdist,
                       const float4* __restrict__ c2c,
                       const float4* __restrict__ cmem,
                       float4* __restrict__ out_inter,
                       float4* __restrict__ out_c2c,
                       float4* __restrict__ out_center,
                       int4* __restrict__ mark) {
    int i = blockIdx.x * blockDim.x + threadIdx.x;
    if (i < N_INTER4) {
        out_inter[i] = interdist[i];
    } else if (i < N_INTER4 + N_C2C4) {
        out_c2c[i - N_INTER4] = c2c[i - N_INTER4];
    } else if (i < N_INTER4 + N_C2C4 + N_CM4) {
        out_center[i - N_INTER4 - N_C2C4] = cmem[i - N_INTER4 - N_C2C4];
    } else if (i < N_INIT4) {
        int4 m; m.x = -1; m.y = -1; m.z = -1; m.w = -1;
        mark[i - N_INTER4 - N_C2C4 - N_CM4] = m;
    }
}

// ---------------- K1a: per-row norms, d1@label -> c2c, seg-sum atomics, feat->bf16,
// ----------------       + scatter mark[index[row]] = row (absorbed k_scatter) ----------------
__global__ void k_rows_a(const float* __restrict__ feat, const float* __restrict__ cmem,
                         const int* __restrict__ label, const int* __restrict__ index,
                         float* __restrict__ out_center, float* __restrict__ out_c2c,
                         float* __restrict__ ws_invf, ushort* __restrict__ fb,
                         int* __restrict__ mark) {
    int wid  = threadIdx.x >> 6;
    int lane = threadIdx.x & 63;
    int row  = blockIdx.x * 4 + wid;
    if (row >= Bb) return;

    const float4 f4 = *(const float4*)(feat + (size_t)row * Dd + lane * 4);
    int lab = label[row];
    const float4 c4 = *(const float4*)(cmem + (size_t)lab * Dd + lane * 4);

    ushort4 h;
    h.x = f2bf(f4.x); h.y = f2bf(f4.y); h.z = f2bf(f4.z); h.w = f2bf(f4.w);
    *(ushort4*)(fb + (size_t)row * Dd + lane * 4) = h;

    float fs = f4.x*f4.x + f4.y*f4.y + f4.z*f4.z + f4.w*f4.w;
    float dt = f4.x*c4.x + f4.y*c4.y + f4.z*c4.z + f4.w*c4.w;
    float cs = c4.x*c4.x + c4.y*c4.y + c4.z*c4.z + c4.w*c4.w;
    #pragma unroll
    for (int off = 32; off; off >>= 1) {
        fs += __shfl_xor(fs, off);
        dt += __shfl_xor(dt, off);
        cs += __shfl_xor(cs, off);
    }
    float invf = 1.0f / fmaxf(sqrtf(fs), EPSV);
    if (lane == 0) {
        ws_invf[row] = invf;
        mark[index[row]] = row;    // scatter (was k_scatter)
        float invc = 1.0f / fmaxf(sqrtf(cs), EPSV);
        float d1 = 0.5f * (1.0f - dt * invf * invc);
        atomicAdd(out_c2c + lab * 2,     1.0f);
        atomicAdd(out_c2c + lab * 2 + 1, d1);
    }
    atomicAdd(out_center + (size_t)lab * Dd + lane * 4 + 0, f4.x);
    atomicAdd(out_center + (size_t)lab * Dd + lane * 4 + 1, f4.y);
    atomicAdd(out_center + (size_t)lab * Dd + lane * 4 + 2, f4.z);
    atomicAdd(out_center + (size_t)lab * Dd + lane * 4 + 3, f4.w);
}

// ---------------- K2: normalize center_new -> chat (f32) + chat_bf16 (padded to 1024) ----------------
__global__ void k_chat(const float* __restrict__ out_center, float* __restrict__ chat,
                       ushort* __restrict__ cb) {
    int c = blockIdx.x;      // 0..1023
    int lane = threadIdx.x;  // 64
    if (c >= Cc) {
        ushort4 z; z.x = 0; z.y = 0; z.z = 0; z.w = 0;
        *(ushort4*)(cb + (size_t)c * Dd + lane * 4) = z;
        return;
    }
    float4 v = *(const float4*)(out_center + (size_t)c * Dd + lane * 4);
    float ss = v.x*v.x + v.y*v.y + v.z*v.z + v.w*v.w;
    #pragma unroll
    for (int off = 32; off; off >>= 1) ss += __shfl_xor(ss, off);
    float inv = 1.0f / fmaxf(sqrtf(ss), EPSV);
    float4 r; r.x = v.x*inv; r.y = v.y*inv; r.z = v.z*inv; r.w = v.w*inv;
    *(float4*)(chat + (size_t)c * Dd + lane * 4) = r;
    ushort4 h;
    h.x = f2bf(r.x); h.y = f2bf(r.y); h.z = f2bf(r.z); h.w = f2bf(r.w);
    *(ushort4*)(cb + (size_t)c * Dd + lane * 4) = h;
}

// ---------------- K4: LDS-staged bf16 MFMA GEMM (R6-proven), scores fp16 out ----------------
// Block tile 128x128, BK=64, 4 waves each owning a 64x64 quadrant. XOR-swizzled LDS
// via pre-swizzled global source (rule 21). R10: launch_bounds(256,3) -> 3 blocks/CU
// (was 2): cross-block overlap hides the vmcnt(0)+barrier drain (m114). VGPR cap 170,
// kernel needs ~110 -> no spill (spill tell = WRITE_SIZE inflation; R3 386MB, R8 189MB).
__global__ __launch_bounds__(256, 3) void k_gemm(const ushort* __restrict__ fb,
                                                 const ushort* __restrict__ cb,
                                                 _Float16* __restrict__ scores) {
    __shared__ __align__(16) char Asb[128 * 128];   // 16 KB
    __shared__ __align__(16) char Bsb[128 * 128];   // 16 KB

    int tid  = threadIdx.x;
    int wid  = tid >> 6;
    int lane = tid & 63;
    int rl = lane & 15;
    int kg = lane >> 4;
    int wr = wid >> 1;          // 0..1 row half
    int wc = wid & 1;           // 0..1 col half
    int row0 = blockIdx.y * 128;
    int c0   = blockIdx.x * 128;

    // pre-swizzled source chunk: lane writes physical chunk (lane&7) of LDS row
    // rloc+(lane>>3); it must fetch logical chunk (lane&7)^(lane>>3)
    int realb = ((lane & 7) ^ (lane >> 3)) << 4;    // byte offset within 128B row

    f32x4 acc[4][4];
    f32x4 z = {0.f, 0.f, 0.f, 0.f};
    #pragma unroll
    for (int mi = 0; mi < 4; mi++)
        #pragma unroll
        for (int ni = 0; ni < 4; ni++)
            acc[mi][ni] = z;

    for (int t = 0; t < 4; t++) {           // K steps of 64
        // ---- stage: each wave loads 32 rows of A and of B (4 issues each, 8 rows/issue)
        #pragma unroll
        for (int i = 0; i < 4; i++) {
            int rloc = wid * 32 + i * 8;
            int grow = row0 + rloc + (lane >> 3);
            gload16((const char*)(fb + (size_t)grow * Dd) + t * 128 + realb,
                    Asb + rloc * 128);
        }
        #pragma unroll
        for (int i = 0; i < 4; i++) {
            int rloc = wid * 32 + i * 8;
            int gcol = c0 + rloc + (lane >> 3);
            gload16((const char*)(cb + (size_t)gcol * Dd) + t * 128 + realb,
                    Bsb + rloc * 128);
        }
        asm volatile("s_waitcnt vmcnt(0)" ::: "memory");
        __syncthreads();

        // ---- fragments: swizzled ds_read_b128
        bf16x8 a[4][2], b[4][2];
        #pragma unroll
        for (int mi = 0; mi < 4; mi++)
            #pragma unroll
            for (int ks = 0; ks < 2; ks++) {
                int r = wr * 64 + mi * 16 + rl;
                int off = r * 128 + ((ks * 64 + kg * 16) ^ ((r & 7) << 4));
                a[mi][ks] = *(const bf16x8*)(Asb + off);
            }
        #pragma unroll
        for (int ni = 0; ni < 4; ni++)
            #pragma unroll
            for (int ks = 0; ks < 2; ks++) {
                int r = wc * 64 + ni * 16 + rl;
                int off = r * 128 + ((ks * 64 + kg * 16) ^ ((r & 7) << 4));
                b[ni][ks] = *(const bf16x8*)(Bsb + off);
            }

        // ---- 32 MFMAs
        #pragma unroll
        for (int ks = 0; ks < 2; ks++)
            #pragma unroll
            for (int mi = 0; mi < 4; mi++)
                #pragma unroll
                for (int ni = 0; ni < 4; ni++)
                    acc[mi][ni] = __builtin_amdgcn_mfma_f32_16x16x32_bf16(
                        a[mi][ks], b[ni][ks], acc[mi][ni], 0, 0, 0);

        __syncthreads();   // before next stage overwrites LDS
    }

    // ---- epilogue: C/D layout col=lane&15, row=(lane>>4)*4+reg [m89]; fp16 stores
    #pragma unroll
    for (int mi = 0; mi < 4; mi++) {
        int row = row0 + wr * 64 + mi * 16 + kg * 4;
        #pragma unroll
        for (int ni = 0; ni < 4; ni++) {
            int col = c0 + wc * 64 + ni * 16 + rl;
            #pragma unroll
            for (int rr = 0; rr < 4; rr++)
                scores[(size_t)(row + rr) * Cpad + col] = (_Float16)acc[mi][ni][rr];
        }
    }
}

// ---------------- K5: per-row exact top-2 of fp16 scores + f32 rescore of near-top candidates ----------------
__global__ __launch_bounds__(256) void k_sel(const _Float16* __restrict__ scores,
                                             const float* __restrict__ feat,
                                             const float* __restrict__ chat,
                                             const float* __restrict__ ws_invf,
                                             float* __restrict__ out_inter) {
    __shared__ int cnt[4];
    __shared__ int clist[4][32];
    int wid  = threadIdx.x >> 6;
    int lane = threadIdx.x & 63;
    int row  = blockIdx.x * 4 + wid;
    if (lane == 0) cnt[wid] = 0;

    const f16x8* sp = (const f16x8*)(scores + (size_t)row * Cpad);
    float v[16];
    float s1 = NEG_BIG, s2 = NEG_BIG;
    int   i1 = IDX_BIG, i2 = IDX_BIG;
    #pragma unroll
    for (int k = 0; k < 2; k++) {
        f16x8 q = sp[k * 64 + lane];            // cols k*512 + lane*8 .. +7 (coalesced 16B)
        int cbase = k * 512 + lane * 8;
        #pragma unroll
        for (int e = 0; e < 8; e++) {
            float f = (float)q[e];
            v[k*8 + e] = f;
            int c = cbase + e;
            if (c < Cc) upd_top2(s1, i1, s2, i2, f, c);
        }
    }
    // butterfly merge (disjoint column sets per lane -> no duplicate insertions)
    #pragma unroll
    for (int off = 1; off < 64; off <<= 1) {
        float ps1 = __shfl_xor(s1, off), ps2 = __shfl_xor(s2, off);
        int   pi1 = __shfl_xor(i1, off), pi2 = __shfl_xor(i2, off);
        upd_top2(s1, i1, s2, i2, ps1, pi1);
        upd_top2(s1, i1, s2, i2, ps2, pi2);
    }
    // candidates: every col with approx score within EPSC of the 2nd max
    float thr = s2 - EPSC;
    #pragma unroll
    for (int j = 0; j < 16; j++) {
        int c = (j >> 3) * 512 + lane * 8 + (j & 7);
        if (v[j] >= thr && c < Cc) {
            int slot = atomicAdd(&cnt[wid], 1);
            if (slot < 32) clist[wid][slot] = c;
        }
    }
    __syncthreads();
    int n = cnt[wid]; if (n > 32) n = 32;

    const float4 f4 = *(const float4*)(feat + (size_t)row * Dd + lane * 4);
    float S1 = NEG_BIG, S2 = NEG_BIG;
    int   I1 = IDX_BIG, I2 = IDX_BIG;
    for (int k = 0; k < n; k++) {
        int c = clist[wid][k];
        const float4 c4 = *(const float4*)(chat + (size_t)c * Dd + lane * 4);
        float d = f4.x*c4.x + f4.y*c4.y + f4.z*c4.z + f4.w*c4.w;
        #pragma unroll
        for (int off = 32; off; off >>= 1) d += __shfl_xor(d, off);
        upd_top2(S1, I1, S2, I2, d, c);   // order-independent result
    }
    if (lane == 0) {
        float inter = 0.5f * ws_invf[row] * (S1 - S2);
        size_t off2 = ((size_t)I1 * Cc + I2) * 2;
        atomicAdd(out_inter + off2,     1.0f);
        atomicAdd(out_inter + off2 + 1, inter);
    }
}

// ---------------- K3: single-pass source_mem copy/lerp (NT on the 410MB stream) ----------------
__global__ void k_src(const float* __restrict__ src, const float* __restrict__ feat,
                      const int* __restrict__ mark, float* __restrict__ dst) {
    const int n4 = NSs * Dd / 4;   // 12,800,000
    int stride = gridDim.x * blockDim.x;
    for (int e = blockIdx.x * blockDim.x + threadIdx.x; e < n4; e += stride) {
        int row = e >> 6;            // Dd/4 = 64 float4 per row; wave-uniform
        int m = mark[row];
        f32x4 v = __builtin_nontemporal_load((const f32x4*)src + e);
        if (m >= 0) {
            f32x4 f = *((const f32x4*)feat + (size_t)m * 64 + (e & 63));
            v = (1.0f - MOM) * v + MOM * f;
        }
        __builtin_nontemporal_store(v, (f32x4*)dst + e);
    }
}

extern "C" void kernel_launch(void* const* d_in, const int* in_sizes, int n_in,
                              void* d_out, int out_size, void* d_ws, size_t ws_size,
                              hipStream_t stream) {
    const float* feat   = (const float*)d_in[0];
    const float* cmem   = (const float*)d_in[1];
    const float* smem   = (const float*)d_in[2];
    const float* c2c    = (const float*)d_in[3];
    const float* inter  = (const float*)d_in[4];
    const int*   label  = (const int*)d_in[5];
    const int*   index  = (const int*)d_in[6];

    float* out = (float*)d_out;
    float* out_center = out + OUT_CENTER;
    float* out_src    = out + OUT_SRC;
    float* out_c2c    = out + OUT_C2C;
    float* out_inter  = out + OUT_INTER;

    float* ws    = (float*)d_ws;
    float* chat  = ws + WS_CHAT;
    float* winvf = ws + WS_INVF;
    int*   mark  = (int*)(ws + WS_MARK);

    // scratch inside out_src region (consumed by k_sel before k_src overwrites)
    _Float16* scores = (_Float16*)(out_src + SCR_SCORES);
    ushort*   fb     = (ushort*)(out_src + SCR_FB);
    ushort*   cb     = (ushort*)(out_src + SCR_CB);

    // 1) base copies + mark init
    k_init<<<(N_INIT4 + 255) / 256, 256, 0, stream>>>(
        (const float4*)inter, (const float4*)c2c, (const float4*)cmem,
        (float4*)out_inter, (float4*)out_c2c, (float4*)out_center,
        (int4*)mark);
    // 2) per-row norms, c2c, center atomics, feat->bf16, mark scatter
    k_rows_a<<<Bb / 4, 256, 0, stream>>>(feat, cmem, label, index,
                                         out_center, out_c2c, winvf, fb, mark);
    // 3) normalize center_new -> chat + chat_bf16 (padded)
    k_chat<<<Cpad, 64, 0, stream>>>(out_center, chat, cb);
    // 4) LDS-staged MFMA GEMM -> fp16 scores
    {
        dim3 grid(Cpad / 128, Bb / 128);   // (8, 128)
        k_gemm<<<grid, 256, 0, stream>>>(fb, cb, scores);
    }
    // 5) top-2 + f32 rescore -> interdist atomics (before scratch is overwritten)
    k_sel<<<Bb / 4, 256, 0, stream>>>(scores, feat, chat, winvf, out_inter);
    // 6) single-pass source_mem copy/lerp (overwrites scratch region)
    k_src<<<4096, 256, 0, stream>>>(smem, feat, mark, out_src);
}

// Round 11
// 253.067 us; speedup vs baseline: 1.4267x; 1.0328x over previous
//
#include <hip/hip_runtime.h>
#include <math.h>

#define Cc 1000
#define Cpad 1024
#define Dd 256
#define Bb 16384
#define NSs 200000
#define MOM 0.1f
#define EPSV 1e-12f
#define EPSC 0.10f
#define NEG_BIG (-3.4e38f)
#define IDX_BIG 0x7fffffff

// d_out layout (floats), concat of reference return tuple
#define OUT_CENTER 0
#define OUT_SRC (Cc*Dd)                       // 256000
#define OUT_C2C (OUT_SRC + (size_t)NSs*Dd)    // 51,456,000
#define OUT_INTER (OUT_C2C + Cc*2)            // 51,458,000

// scratch inside out_src region (float offsets); occupies rows [0, SAFE_ROW) of out_src.
// Rows >= SAFE_ROW are copy-safe DURING the gemm; rows < SAFE_ROW copied after k_sel.
#define SCR_SCORES 0                           // _Float16[Bb*Cpad] = 8,388,608 floats
#define SCR_FB 8388608                         // ushort[Bb*Dd]   (2,097,152 floats)
#define SCR_CB (SCR_FB + 2097152)              // ushort[Cpad*Dd] (131,072 floats)
#define SCR_END 10616832                       // = 41472 rows * 256
#define SAFE_ROW 41472
#define E0 (SAFE_ROW * 64)                     // first copy-safe float4: 2,654,208
#define N4ALL (NSs * 64)                       // 12,800,000 float4 total

// ws layout (floats) — total ~1.85 MB (proven)
#define WS_CHAT 0
#define WS_INVF 256000
#define WS_MARK 272384                         // int[NSs]

typedef __bf16    bf16x8 __attribute__((ext_vector_type(8)));
typedef float     f32x4  __attribute__((ext_vector_type(4)));
typedef _Float16  f16x8  __attribute__((ext_vector_type(8)));

__device__ __forceinline__ ushort f2bf(float f) {
    uint u = __float_as_uint(f);
    u += 0x7FFFu + ((u >> 16) & 1u);   // round-to-nearest-even
    return (ushort)(u >> 16);
}

__device__ __forceinline__ void gload16(const void* g, void* l) {
    __builtin_amdgcn_global_load_lds(
        (const __attribute__((address_space(1))) void*)g,
        (__attribute__((address_space(3))) void*)l, 16, 0, 0);
}

__device__ __forceinline__ void upd_top2(float& s1, int& i1, float& s2, int& i2,
                                         float s, int i) {
    // jax.lax.top_k tie semantics: larger value first; equal values -> lower index first
    if (s > s1 || (s == s1 && i < i1)) {
        s2 = s1; i2 = i1; s1 = s; i1 = i;
    } else if (s > s2 || (s == s2 && i < i2)) {
        s2 = s; i2 = i;
    }
}

__device__ __forceinline__ void copy_range(const float* __restrict__ src,
                                           const float* __restrict__ feat,
                                           const int* __restrict__ mark,
                                           float* __restrict__ dst,
                                           int e0, int e1, int tid0, int nthreads) {
    for (int e = e0 + tid0; e < e1; e += nthreads) {
        int row = e >> 6;            // 64 float4 per row; wave-uniform
        int m = mark[row];
        f32x4 v = __builtin_nontemporal_load((const f32x4*)src + e);
        if (m >= 0) {
            f32x4 f = *((const f32x4*)feat + (size_t)m * 64 + (e & 63));
            v = (1.0f - MOM) * v + MOM * f;
        }
        __builtin_nontemporal_store(v, (f32x4*)dst + e);
    }
}

// ---------------- K_init: base copies (inter, c2c, center) + mark=-1 ----------------
#define N_INTER4 (Cc*Cc*2/4)     // 500000
#define N_C2C4   (Cc*2/4)        // 500
#define N_CM4    (Cc*Dd/4)       // 64000
#define N_MARK4  (NSs/4)         // 50000
#define N_INIT4  (N_INTER4 + N_C2C4 + N_CM4 + N_MARK4)

__global__ void k_init(const float4* __restrict__ interdist,
                       const float4* __restrict__ c2c,
                       const float4* __restrict__ cmem,
                       float4* __restrict__ out_inter,
                       float4* __restrict__ out_c2c,
                       float4* __restrict__ out_center,
                       int4* __restrict__ mark) {
    int i = blockIdx.x * blockDim.x + threadIdx.x;
    if (i < N_INTER4) {
        out_inter[i] = interdist[i];
    } else if (i < N_INTER4 + N_C2C4) {
        out_c2c[i - N_INTER4] = c2c[i - N_INTER4];
    } else if (i < N_INTER4 + N_C2C4 + N_CM4) {
        out_center[i - N_INTER4 - N_C2C4] = cmem[i - N_INTER4 - N_C2C4];
    } else if (i < N_INIT4) {
        int4 m; m.x = -1; m.y = -1; m.z = -1; m.w = -1;
        mark[i - N_INTER4 - N_C2C4 - N_CM4] = m;
    }
}

// ---------------- K1a: per-row norms, d1@label -> c2c, seg-sum atomics, feat->bf16,
// ----------------       + scatter mark[index[row]] = row ----------------
__global__ void k_rows_a(const float* __restrict__ feat, const float* __restrict__ cmem,
                         const int* __restrict__ label, const int* __restrict__ index,
                         float* __restrict__ out_center, float* __restrict__ out_c2c,
                         float* __restrict__ ws_invf, ushort* __restrict__ fb,
                         int* __restrict__ mark) {
    int wid  = threadIdx.x >> 6;
    int lane = threadIdx.x & 63;
    int row  = blockIdx.x * 4 + wid;
    if (row >= Bb) return;

    const float4 f4 = *(const float4*)(feat + (size_t)row * Dd + lane * 4);
    int lab = label[row];
    const float4 c4 = *(const float4*)(cmem + (size_t)lab * Dd + lane * 4);

    ushort4 h;
    h.x = f2bf(f4.x); h.y = f2bf(f4.y); h.z = f2bf(f4.z); h.w = f2bf(f4.w);
    *(ushort4*)(fb + (size_t)row * Dd + lane * 4) = h;

    float fs = f4.x*f4.x + f4.y*f4.y + f4.z*f4.z + f4.w*f4.w;
    float dt = f4.x*c4.x + f4.y*c4.y + f4.z*c4.z + f4.w*c4.w;
    float cs = c4.x*c4.x + c4.y*c4.y + c4.z*c4.z + c4.w*c4.w;
    #pragma unroll
    for (int off = 32; off; off >>= 1) {
        fs += __shfl_xor(fs, off);
        dt += __shfl_xor(dt, off);
        cs += __shfl_xor(cs, off);
    }
    float invf = 1.0f / fmaxf(sqrtf(fs), EPSV);
    if (lane == 0) {
        ws_invf[row] = invf;
        mark[index[row]] = row;
        float invc = 1.0f / fmaxf(sqrtf(cs), EPSV);
        float d1 = 0.5f * (1.0f - dt * invf * invc);
        atomicAdd(out_c2c + lab * 2,     1.0f);
        atomicAdd(out_c2c + lab * 2 + 1, d1);
    }
    atomicAdd(out_center + (size_t)lab * Dd + lane * 4 + 0, f4.x);
    atomicAdd(out_center + (size_t)lab * Dd + lane * 4 + 1, f4.y);
    atomicAdd(out_center + (size_t)lab * Dd + lane * 4 + 2, f4.z);
    atomicAdd(out_center + (size_t)lab * Dd + lane * 4 + 3, f4.w);
}

// ---------------- K2: normalize center_new -> chat (f32) + chat_bf16 (padded to 1024) ----------------
__global__ void k_chat(const float* __restrict__ out_center, float* __restrict__ chat,
                       ushort* __restrict__ cb) {
    int c = blockIdx.x;      // 0..1023
    int lane = threadIdx.x;  // 64
    if (c >= Cc) {
        ushort4 z; z.x = 0; z.y = 0; z.z = 0; z.w = 0;
        *(ushort4*)(cb + (size_t)c * Dd + lane * 4) = z;
        return;
    }
    float4 v = *(const float4*)(out_center + (size_t)c * Dd + lane * 4);
    float ss = v.x*v.x + v.y*v.y + v.z*v.z + v.w*v.w;
    #pragma unroll
    for (int off = 32; off; off >>= 1) ss += __shfl_xor(ss, off);
    float inv = 1.0f / fmaxf(sqrtf(ss), EPSV);
    float4 r; r.x = v.x*inv; r.y = v.y*inv; r.z = v.z*inv; r.w = v.w*inv;
    *(float4*)(chat + (size_t)c * Dd + lane * 4) = r;
    ushort4 h;
    h.x = f2bf(r.x); h.y = f2bf(r.y); h.z = f2bf(r.z); h.w = f2bf(r.w);
    *(ushort4*)(cb + (size_t)c * Dd + lane * 4) = h;
}

// ---------------- K4: role-split kernel: GEMM tiles (b%4==0) CONCURRENT WITH
// ----------------      NT copy/lerp of out_src rows >= SAFE_ROW (b%4!=0) ----------------
// GEMM: R10-proven 128x128/BK=64 XOR-swizzled LDS MFMA, fp16 scores out.
// Copy: grid-stride over float4s [E0, N4ALL) — independent of scratch (rows < SAFE_ROW),
// only needs mark (prior dispatch). MFMA pipe and HBM pipe co-schedule per m114; this
// converts gemm_time + copy_time into ~max() on one stream without multi-stream capture.
#define GEMM_BLKS 1024                 // 8 x 128 tiles
#define COPY_BLKS 3072
#define TOTAL_BLKS 4096

__global__ __launch_bounds__(256, 3) void k_gemm_copy(const ushort* __restrict__ fb,
                                                      const ushort* __restrict__ cb,
                                                      _Float16* __restrict__ scores,
                                                      const float* __restrict__ smem,
                                                      const float* __restrict__ feat,
                                                      const int* __restrict__ mark,
                                                      float* __restrict__ out_src) {
    __shared__ __align__(16) char Asb[128 * 128];   // 16 KB
    __shared__ __align__(16) char Bsb[128 * 128];   // 16 KB

    int b = blockIdx.x;
    if ((b & 3) != 0) {
        // ---------- copy role: 3072 blocks, float4s [E0, N4ALL) ----------
        int c = (b - (b >> 2)) - 1;            // contiguous 0..3071 over b%4!=0
        int tid0 = c * 256 + threadIdx.x;
        copy_range(smem, feat, mark, out_src, E0, N4ALL, tid0, COPY_BLKS * 256);
        return;
    }
    int g = b >> 2;                             // 0..1023 gemm tile id
    int bx = g & 7;                             // col tile (Cpad/128)
    int by = g >> 3;                            // row tile (Bb/128)

    int tid  = threadIdx.x;
    int wid  = tid >> 6;
    int lane = tid & 63;
    int rl = lane & 15;
    int kg = lane >> 4;
    int wr = wid >> 1;          // 0..1 row half
    int wc = wid & 1;           // 0..1 col half
    int row0 = by * 128;
    int c0   = bx * 128;

    // pre-swizzled source chunk: lane writes physical chunk (lane&7) of LDS row
    // rloc+(lane>>3); it must fetch logical chunk (lane&7)^(lane>>3)
    int realb = ((lane & 7) ^ (lane >> 3)) << 4;    // byte offset within 128B row

    f32x4 acc[4][4];
    f32x4 z = {0.f, 0.f, 0.f, 0.f};
    #pragma unroll
    for (int mi = 0; mi < 4; mi++)
        #pragma unroll
        for (int ni = 0; ni < 4; ni++)
            acc[mi][ni] = z;

    for (int t = 0; t < 4; t++) {           // K steps of 64
        #pragma unroll
        for (int i = 0; i < 4; i++) {
            int rloc = wid * 32 + i * 8;
            int grow = row0 + rloc + (lane >> 3);
            gload16((const char*)(fb + (size_t)grow * Dd) + t * 128 + realb,
                    Asb + rloc * 128);
        }
        #pragma unroll
        for (int i = 0; i < 4; i++) {
            int rloc = wid * 32 + i * 8;
            int gcol = c0 + rloc + (lane >> 3);
            gload16((const char*)(cb + (size_t)gcol * Dd) + t * 128 + realb,
                    Bsb + rloc * 128);
        }
        asm volatile("s_waitcnt vmcnt(0)" ::: "memory");
        __syncthreads();

        // ---- fragments: swizzled ds_read_b128
        bf16x8 a[4][2], bfr[4][2];
        #pragma unroll
        for (int mi = 0; mi < 4; mi++)
            #pragma unroll
            for (int ks = 0; ks < 2; ks++) {
                int r = wr * 64 + mi * 16 + rl;
                int off = r * 128 + ((ks * 64 + kg * 16) ^ ((r & 7) << 4));
                a[mi][ks] = *(const bf16x8*)(Asb + off);
            }
        #pragma unroll
        for (int ni = 0; ni < 4; ni++)
            #pragma unroll
            for (int ks = 0; ks < 2; ks++) {
                int r = wc * 64 + ni * 16 + rl;
                int off = r * 128 + ((ks * 64 + kg * 16) ^ ((r & 7) << 4));
                bfr[ni][ks] = *(const bf16x8*)(Bsb + off);
            }

        // ---- 32 MFMAs
        #pragma unroll
        for (int ks = 0; ks < 2; ks++)
            #pragma unroll
            for (int mi = 0; mi < 4; mi++)
                #pragma unroll
                for (int ni = 0; ni < 4; ni++)
                    acc[mi][ni] = __builtin_amdgcn_mfma_f32_16x16x32_bf16(
                        a[mi][ks], bfr[ni][ks], acc[mi][ni], 0, 0, 0);

        __syncthreads();   // before next stage overwrites LDS
    }

    // ---- epilogue: C/D layout col=lane&15, row=(lane>>4)*4+reg [m89]; fp16 stores
    #pragma unroll
    for (int mi = 0; mi < 4; mi++) {
        int row = row0 + wr * 64 + mi * 16 + kg * 4;
        #pragma unroll
        for (int ni = 0; ni < 4; ni++) {
            int col = c0 + wc * 64 + ni * 16 + rl;
            #pragma unroll
            for (int rr = 0; rr < 4; rr++)
                scores[(size_t)(row + rr) * Cpad + col] = (_Float16)acc[mi][ni][rr];
        }
    }
}

// ---------------- K5: per-row exact top-2 of fp16 scores + f32 rescore of near-top candidates ----------------
__global__ __launch_bounds__(256) void k_sel(const _Float16* __restrict__ scores,
                                             const float* __restrict__ feat,
                                             const float* __restrict__ chat,
                                             const float* __restrict__ ws_invf,
                                             float* __restrict__ out_inter) {
    __shared__ int cnt[4];
    __shared__ int clist[4][32];
    int wid  = threadIdx.x >> 6;
    int lane = threadIdx.x & 63;
    int row  = blockIdx.x * 4 + wid;
    if (lane == 0) cnt[wid] = 0;

    const f16x8* sp = (const f16x8*)(scores + (size_t)row * Cpad);
    float v[16];
    float s1 = NEG_BIG, s2 = NEG_BIG;
    int   i1 = IDX_BIG, i2 = IDX_BIG;
    #pragma unroll
    for (int k = 0; k < 2; k++) {
        f16x8 q = sp[k * 64 + lane];            // cols k*512 + lane*8 .. +7 (coalesced 16B)
        int cbase = k * 512 + lane * 8;
        #pragma unroll
        for (int e = 0; e < 8; e++) {
            float f = (float)q[e];
            v[k*8 + e] = f;
            int c = cbase + e;
            if (c < Cc) upd_top2(s1, i1, s2, i2, f, c);
        }
    }
    // butterfly merge (disjoint column sets per lane -> no duplicate insertions)
    #pragma unroll
    for (int off = 1; off < 64; off <<= 1) {
        float ps1 = __shfl_xor(s1, off), ps2 = __shfl_xor(s2, off);
        int   pi1 = __shfl_xor(i1, off), pi2 = __shfl_xor(i2, off);
        upd_top2(s1, i1, s2, i2, ps1, pi1);
        upd_top2(s1, i1, s2, i2, ps2, pi2);
    }
    // candidates: every col with approx score within EPSC of the 2nd max
    float thr = s2 - EPSC;
    #pragma unroll
    for (int j = 0; j < 16; j++) {
        int c = (j >> 3) * 512 + lane * 8 + (j & 7);
        if (v[j] >= thr && c < Cc) {
            int slot = atomicAdd(&cnt[wid], 1);
            if (slot < 32) clist[wid][slot] = c;
        }
    }
    __syncthreads();
    int n = cnt[wid]; if (n > 32) n = 32;

    const float4 f4 = *(const float4*)(feat + (size_t)row * Dd + lane * 4);
    float S1 = NEG_BIG, S2 = NEG_BIG;
    int   I1 = IDX_BIG, I2 = IDX_BIG;
    for (int k = 0; k < n; k++) {
        int c = clist[wid][k];
        const float4 c4 = *(const float4*)(chat + (size_t)c * Dd + lane * 4);
        float d = f4.x*c4.x + f4.y*c4.y + f4.z*c4.z + f4.w*c4.w;
        #pragma unroll
        for (int off = 32; off; off >>= 1) d += __shfl_xor(d, off);
        upd_top2(S1, I1, S2, I2, d, c);   // order-independent result
    }
    if (lane == 0) {
        float inter = 0.5f * ws_invf[row] * (S1 - S2);
        size_t off2 = ((size_t)I1 * Cc + I2) * 2;
        atomicAdd(out_inter + off2,     1.0f);
        atomicAdd(out_inter + off2 + 1, inter);
    }
}

// ---------------- K3b: copy/lerp remaining rows [0, SAFE_ROW) over the dead scratch ----------------
__global__ void k_src2(const float* __restrict__ src, const float* __restrict__ feat,
                       const int* __restrict__ mark, float* __restrict__ dst) {
    int tid0 = blockIdx.x * blockDim.x + threadIdx.x;
    copy_range(src, feat, mark, dst, 0, E0, tid0, gridDim.x * blockDim.x);
}

extern "C" void kernel_launch(void* const* d_in, const int* in_sizes, int n_in,
                              void* d_out, int out_size, void* d_ws, size_t ws_size,
                              hipStream_t stream) {
    const float* feat   = (const float*)d_in[0];
    const float* cmem   = (const float*)d_in[1];
    const float* smem   = (const float*)d_in[2];
    const float* c2c    = (const float*)d_in[3];
    const float* inter  = (const float*)d_in[4];
    const int*   label  = (const int*)d_in[5];
    const int*   index  = (const int*)d_in[6];

    float* out = (float*)d_out;
    float* out_center = out + OUT_CENTER;
    float* out_src    = out + OUT_SRC;
    float* out_c2c    = out + OUT_C2C;
    float* out_inter  = out + OUT_INTER;

    float* ws    = (float*)d_ws;
    float* chat  = ws + WS_CHAT;
    float* winvf = ws + WS_INVF;
    int*   mark  = (int*)(ws + WS_MARK);

    // scratch inside out_src region rows [0, SAFE_ROW); consumed by k_sel, then k_src2 overwrites
    _Float16* scores = (_Float16*)(out_src + SCR_SCORES);
    ushort*   fb     = (ushort*)(out_src + SCR_FB);
    ushort*   cb     = (ushort*)(out_src + SCR_CB);

    // 1) base copies + mark init
    k_init<<<(N_INIT4 + 255) / 256, 256, 0, stream>>>(
        (const float4*)inter, (const float4*)c2c, (const float4*)cmem,
        (float4*)out_inter, (float4*)out_c2c, (float4*)out_center,
        (int4*)mark);
    // 2) per-row norms, c2c, center atomics, feat->bf16, mark scatter
    k_rows_a<<<Bb / 4, 256, 0, stream>>>(feat, cmem, label, index,
                                         out_center, out_c2c, winvf, fb, mark);
    // 3) normalize center_new -> chat + chat_bf16 (padded)
    k_chat<<<Cpad, 64, 0, stream>>>(out_center, chat, cb);
    // 4) GEMM tiles CONCURRENT WITH copy of out_src rows >= SAFE_ROW
    k_gemm_copy<<<TOTAL_BLKS, 256, 0, stream>>>(fb, cb, scores,
                                                smem, feat, mark, out_src);
    // 5) top-2 + f32 rescore -> interdist atomics (scores still live)
    k_sel<<<Bb / 4, 256, 0, stream>>>(scores, feat, chat, winvf, out_inter);
    // 6) copy rows [0, SAFE_ROW) over the dead scratch
    k_src2<<<2048, 256, 0, stream>>>(smem, feat, mark, out_src);
}